// Round 2
// baseline (624.882 us; speedup 1.0000x reference)
//
#include <hip/hip_runtime.h>
#include <cstdint>
#include <cstddef>

#define E_ 8
#define D_ 768
#define F_ 3072
#define N_ 16384
#define CAP_ 2560   // int(1.25 * 16384 / 8)
#define NCHUNK_ (N_ / 256)   // 64

typedef __attribute__((ext_vector_type(8))) short bf16x8;
typedef __attribute__((ext_vector_type(4))) float f32x4;

__device__ __forceinline__ unsigned short f2bf(float f) {
  unsigned u = __float_as_uint(f);
  u += 0x7fffu + ((u >> 16) & 1u);   // round-to-nearest-even
  return (unsigned short)(u >> 16);
}

__device__ __forceinline__ void gload16(const void* g, void* l) {
  __builtin_amdgcn_global_load_lds(
      (const __attribute__((address_space(1))) void*)g,
      (__attribute__((address_space(3))) void*)l, 16, 0, 0);
}

// ---------------- transpose + cast weights: src [E][R][C] fp32 -> dst [E][C][R] bf16 ----------------
__global__ void tcast_kernel(const float* __restrict__ src, unsigned short* __restrict__ dst,
                             int R, int C) {
  __shared__ float tile[64][65];
  int e = blockIdx.z;
  const float* s = src + (size_t)e * R * C;
  unsigned short* d = dst + (size_t)e * R * C;
  int c0 = blockIdx.x * 64, r0 = blockIdx.y * 64;
  int tx = threadIdx.x, ty = threadIdx.y;
  #pragma unroll
  for (int rr = ty; rr < 64; rr += 8) {
    tile[rr][tx]      = s[(size_t)(r0 + rr) * C + c0 + tx];
    tile[rr][tx + 32] = s[(size_t)(r0 + rr) * C + c0 + tx + 32];
  }
  __syncthreads();
  #pragma unroll
  for (int cc = ty; cc < 64; cc += 8) {
    ushort2 o;
    o.x = f2bf(tile[2 * tx][cc]);
    o.y = f2bf(tile[2 * tx + 1][cc]);
    *(ushort2*)&d[(size_t)(c0 + cc) * R + r0 + 2 * tx] = o;
  }
}

// ---------------- router (fused x->bf16 cast) ----------------
__global__ __launch_bounds__(256) void router_kernel(
    const float* __restrict__ x, const float* __restrict__ sw, const float* __restrict__ sb,
    int* __restrict__ route, float* __restrict__ prob,
    unsigned short* __restrict__ xb) {
  __shared__ float wl[E_ * D_];
  int tid = threadIdx.x;
  #pragma unroll
  for (int ee = 0; ee < E_; ++ee)
    for (int dd = tid; dd < D_; dd += 256)
      wl[ee * D_ + dd] = sw[dd * E_ + ee];
  __syncthreads();
  int wave = tid >> 6, lane = tid & 63;
  int tbase = blockIdx.x * 16 + wave * 4;
  #pragma unroll
  for (int tt = 0; tt < 4; ++tt) {
    int t = tbase + tt;
    const float* xp = x + (size_t)t * D_;
    unsigned short* xbp = xb + (size_t)t * D_;
    float acc[E_];
    #pragma unroll
    for (int e = 0; e < E_; ++e) acc[e] = 0.f;
    #pragma unroll
    for (int r = 0; r < D_ / 64; ++r) {
      int dd = r * 64 + lane;
      float xv = xp[dd];
      xbp[dd] = f2bf(xv);
      #pragma unroll
      for (int e = 0; e < E_; ++e) acc[e] += xv * wl[e * D_ + dd];
    }
    #pragma unroll
    for (int e = 0; e < E_; ++e) {
      #pragma unroll
      for (int o = 32; o > 0; o >>= 1) acc[e] += __shfl_xor(acc[e], o);
    }
    if (lane == 0) {
      float mx = -1e30f; int arg = 0;
      #pragma unroll
      for (int e = 0; e < E_; ++e) {
        float l = acc[e] + sb[e];
        acc[e] = l;
        if (l > mx) { mx = l; arg = e; }
      }
      float s = 0.f;
      #pragma unroll
      for (int e = 0; e < E_; ++e) s += expf(acc[e] - mx);
      route[t] = arg;
      prob[t] = 1.f / s;
    }
  }
}

// ---------------- per-chunk histogram ----------------
__global__ void hist_kernel(const int* __restrict__ route, int* __restrict__ chunk_hist) {
  __shared__ int h[E_];
  int tid = threadIdx.x;
  if (tid < E_) h[tid] = 0;
  __syncthreads();
  atomicAdd(&h[route[blockIdx.x * 256 + tid]], 1);
  __syncthreads();
  if (tid < E_) chunk_hist[blockIdx.x * E_ + tid] = h[tid];
}

// ---------------- exclusive scan over chunks per expert ----------------
__global__ void scan_kernel(const int* __restrict__ chunk_hist, int* __restrict__ chunk_off,
                            int* __restrict__ counts) {
  __shared__ int h[NCHUNK_ * E_];
  int tid = threadIdx.x;
  h[tid] = chunk_hist[tid];
  __syncthreads();
  if (tid < E_) {
    int run = 0;
    for (int c = 0; c < NCHUNK_; ++c) {
      chunk_off[c * E_ + tid] = run;
      run += h[c * E_ + tid];
    }
    counts[tid] = run;
  }
}

// ---------------- slot assignment ----------------
__global__ void assign_kernel(const int* __restrict__ route, const float* __restrict__ prob,
                              const int* __restrict__ counts, const int* __restrict__ chunk_off,
                              int* __restrict__ tok_list, int* __restrict__ slot) {
  __shared__ int rt[256];
  int tid = threadIdx.x;
  int i = blockIdx.x * 256 + tid;
  int e = route[i];
  rt[tid] = e;
  __syncthreads();
  int r = 0;
  for (int j = 0; j < tid; ++j) r += (rt[j] == e) ? 1 : 0;
  int c = counts[e];
  int s; bool keep;
  if (c <= CAP_) {
    s = chunk_off[blockIdx.x * E_ + e] + r;
    keep = true;
  } else {
    float p = prob[i];
    int rr = 0;
    for (int j = 0; j < N_; ++j) {
      if (route[j] == e) {
        float pj = prob[j];
        rr += (pj > p || (pj == p && j < i)) ? 1 : 0;
      }
    }
    s = rr; keep = (rr < CAP_);
  }
  if (keep) tok_list[e * CAP_ + s] = i;
  slot[i] = keep ? s : -1;
}

// =====================================================================================
// 256x256 / BK=64 grouped GEMMs, 8 waves (2Mx4N), 128 KiB dbuf LDS, TRUE 8-phase
// counted-vmcnt schedule (T3+T4), T2 LDS chunk-swizzle (pre-swizzled global source,
// linear gload_lds dest, XOR on fragment read), T5 setprio, T1 XCD-chunked grid.
//
// Half-tile = 128 rows x 64 k of one matrix = 16 KB = 2 gload16/thread.
// LDS slots per buffer (bytes): A0 @0, A1 @16384, B0 @32768, B1 @49152; buf1 @+65536.
// Phase plan per iteration (tiles T=2i in buf0, T+1 in buf1):
//   ph1: rd buf0 a(i0-3,2kh)+b(j0-1,2kh); stage buf1.A0<-T+1 | MFMA Q(ilo,jlo)
//   ph2: rd buf0 b(j2-3,2kh);             stage buf1.A1<-T+1 | MFMA Q(ilo,jhi)
//   ph3: rd buf0 a(i4-7,2kh);             stage buf0.B0<-T+2 | MFMA Q(ihi,jlo)
//   ph4:                                  stage buf0.B1<-T+2 | MFMA Q(ihi,jhi); vmcnt(4)
//   ph5-8: mirror on buf1; stages buf0.A0,A1<-T+2, buf1.B0,B1<-T+3; vmcnt(4) @ph8.
// vmcnt(4) leaves exactly the 2 newest half-tiles (next tile's B) in flight; every
// slot the upcoming group reads is awaited. Slot-free proof: B-halves last read ph2
// (ph6), A-halves last read ph3 (ph7) -> all stage targets free at issue time.
// =====================================================================================

#define RD_A(dst, cb, i0)                                                         \
  _Pragma("unroll") for (int ii = 0; ii < 4; ++ii)                                \
  _Pragma("unroll") for (int kh = 0; kh < 2; ++kh)                                \
    dst[ii][kh] = *(const bf16x8*)(sm + (cb) * 32768 + wmo +                      \
        ((i0 + ii) * 16 + fr) * 64 + (((kh * 4 + q) ^ fr7) * 8));

#define RD_B(dst, cb, j0)                                                         \
  _Pragma("unroll") for (int jj = 0; jj < 2; ++jj)                                \
  _Pragma("unroll") for (int kh = 0; kh < 2; ++kh)                                \
    dst[jj][kh] = *(const bf16x8*)(sm + (cb) * 32768 + 16384 + wno +              \
        (wn64 + (j0 + jj) * 16 + fr) * 64 + (((kh * 4 + q) ^ fr7) * 8));

#define MM(i0, j0, A_, B_)                                                        \
  _Pragma("unroll") for (int ii = 0; ii < 4; ++ii)                                \
  _Pragma("unroll") for (int jj = 0; jj < 2; ++jj)                                \
  _Pragma("unroll") for (int kh = 0; kh < 2; ++kh)                                \
    acc[i0 + ii][j0 + jj] = __builtin_amdgcn_mfma_f32_16x16x32_bf16(              \
        A_[ii][kh], B_[jj][kh], acc[i0 + ii][j0 + jj], 0, 0, 0);

#define STG_A(tb, h, t) {                                                         \
  gload16(pA##h##0 + (size_t)(t) * 64, smb + (tb) * 65536 + (h) * 16384 + w * 1024);            \
  gload16(pA##h##1 + (size_t)(t) * 64, smb + (tb) * 65536 + (h) * 16384 + 8192 + w * 1024); }

#define STG_B(tb, h, t) {                                                         \
  gload16(pB##h##0 + (size_t)(t) * 64, smb + (tb) * 65536 + 32768 + (h) * 16384 + w * 1024);    \
  gload16(pB##h##1 + (size_t)(t) * 64, smb + (tb) * 65536 + 32768 + (h) * 16384 + 8192 + w * 1024); }

#define BAR __builtin_amdgcn_s_barrier()
#define PRIO1 __builtin_amdgcn_s_setprio(1)
#define PRIO0 __builtin_amdgcn_s_setprio(0)
#define WAITV4 asm volatile("s_waitcnt vmcnt(4)" ::: "memory")

#define GROUP(cb, ta, tgtA, tb_, tgtB)                                            \
  RD_A(alo, cb, 0); RD_B(blo, cb, 0); STG_A(tgtA, 0, ta);                         \
  BAR; PRIO1; MM(0, 0, alo, blo); PRIO0; BAR;                                     \
  RD_B(bhi, cb, 2); STG_A(tgtA, 1, ta);                                           \
  BAR; PRIO1; MM(0, 2, alo, bhi); PRIO0; BAR;                                     \
  RD_A(ahi, cb, 4); STG_B(tgtB, 0, tb_);                                          \
  BAR; PRIO1; MM(4, 0, ahi, blo); PRIO0; BAR;                                     \
  STG_B(tgtB, 1, tb_);                                                            \
  BAR; PRIO1; MM(4, 2, ahi, bhi); PRIO0; WAITV4; BAR;

// ---------------- GEMM1: h[e][m][f] = gelu( x[tok] @ w1[e] + b1[e] ) ----------------
__global__ __launch_bounds__(512, 2) void gemm1_kernel(
    const unsigned short* __restrict__ xb, const unsigned short* __restrict__ w1t,
    const float* __restrict__ b1, const int* __restrict__ tok_list,
    const int* __restrict__ counts, unsigned short* __restrict__ hb) {
  // T1: XCD-chunked swizzle (960 blocks % 8 == 0): XCD k gets expert k's whole GEMM
  int flat = blockIdx.x + 10 * (blockIdx.y + 12 * blockIdx.z);
  int work = (flat & 7) * 120 + (flat >> 3);
  int xm = work % 10;
  int rest = work / 10;
  int yn = rest % 12;
  int e = rest / 12;
  int Me = counts[e] < CAP_ ? counts[e] : CAP_;
  int m0 = xm * 256;
  if (m0 >= Me) return;
  int n0 = yn * 256;
  __shared__ unsigned short sm[65536];   // 128 KiB
  char* smb = (char*)sm;
  int tid = threadIdx.x, lane = tid & 63, w = tid >> 6;
  // staging geometry
  int l8 = lane >> 3;
  int sc = (lane & 7) ^ l8;              // pre-swizzled source chunk
  int rbase = w * 8 + l8;                // 0..63
  int ra00 = m0 + rbase;       if (ra00 > Me - 1) ra00 = Me - 1;
  int ra01 = m0 + 64 + rbase;  if (ra01 > Me - 1) ra01 = Me - 1;
  int ra10 = m0 + 128 + rbase; if (ra10 > Me - 1) ra10 = Me - 1;
  int ra11 = m0 + 192 + rbase; if (ra11 > Me - 1) ra11 = Me - 1;
  const unsigned short* pA00 = xb + (size_t)tok_list[e * CAP_ + ra00] * D_ + sc * 8;
  const unsigned short* pA01 = xb + (size_t)tok_list[e * CAP_ + ra01] * D_ + sc * 8;
  const unsigned short* pA10 = xb + (size_t)tok_list[e * CAP_ + ra10] * D_ + sc * 8;
  const unsigned short* pA11 = xb + (size_t)tok_list[e * CAP_ + ra11] * D_ + sc * 8;
  const unsigned short* pB00 = w1t + ((size_t)e * F_ + n0 + rbase) * D_ + sc * 8;
  const unsigned short* pB01 = w1t + ((size_t)e * F_ + n0 + 64 + rbase) * D_ + sc * 8;
  const unsigned short* pB10 = w1t + ((size_t)e * F_ + n0 + 128 + rbase) * D_ + sc * 8;
  const unsigned short* pB11 = w1t + ((size_t)e * F_ + n0 + 192 + rbase) * D_ + sc * 8;
  // fragment geometry
  int fr = lane & 15, q = lane >> 4, fr7 = fr & 7;
  int wm = (w >> 2) * 128, wn = (w & 3) * 64;
  int wmo = wm * 64;            // A-half select (shorts)
  int wno = (wn & 128) * 64;    // B-half select (shorts)
  int wn64 = wn & 64;           // row base within B-half
  f32x4 acc[8][4] = {};
  bf16x8 alo[4][2], ahi[4][2], blo[2][2], bhi[2][2];

  // prologue: buf0 <- tile0 (all 4 halves), buf1 <- tile1 B-halves
  STG_B(0, 0, 0); STG_B(0, 1, 0); STG_A(0, 0, 0); STG_A(0, 1, 0);
  STG_B(1, 0, 1); STG_B(1, 1, 1);
  WAITV4; BAR;

  const int NT = D_ / 64;   // 12
  for (int it = 0; it < NT / 2; ++it) {
    int t1 = 2 * it + 1, t2 = 2 * it + 2, t3 = 2 * it + 3;
    if (t2 > NT - 1) t2 = NT - 1;    // tail: redundant re-stage into dead slots
    if (t3 > NT - 1) t3 = NT - 1;
    GROUP(0, t1, 1, t2, 0)
    GROUP(1, t2, 0, t3, 1)
  }

  int q4 = q * 4;
  #pragma unroll
  for (int i = 0; i < 8; ++i) {
    #pragma unroll
    for (int j = 0; j < 4; ++j) {
      int col = n0 + wn + j * 16 + fr;
      float bias = b1[e * F_ + col];
      #pragma unroll
      for (int r = 0; r < 4; ++r) {
        int row = m0 + wm + i * 16 + q4 + r;
        if (row < Me) {
          float v = acc[i][j][r] + bias;
          v = 0.5f * v * (1.f + erff(v * 0.70710678118654752f));   // exact GELU
          hb[((size_t)e * CAP_ + row) * F_ + col] = f2bf(v);
        }
      }
    }
  }
}

// ---------------- GEMM2: out[tok] = (h[e] @ w2[e] + b2[e]) * prob[tok] ----------------
__global__ __launch_bounds__(512, 2) void gemm2_kernel(
    const unsigned short* __restrict__ hb, const unsigned short* __restrict__ w2t,
    const float* __restrict__ b2, const int* __restrict__ tok_list,
    const int* __restrict__ counts, const float* __restrict__ prob,
    float* __restrict__ out) {
  // T1 swizzle (240 blocks % 8 == 0)
  int flat = blockIdx.x + 10 * (blockIdx.y + 3 * blockIdx.z);
  int work = (flat & 7) * 30 + (flat >> 3);
  int xm = work % 10;
  int rest = work / 10;
  int yn = rest % 3;
  int e = rest / 3;
  int Me = counts[e] < CAP_ ? counts[e] : CAP_;
  int m0 = xm * 256;
  if (m0 >= Me) return;
  int n0 = yn * 256;
  __shared__ unsigned short sm[65536];
  char* smb = (char*)sm;
  int tid = threadIdx.x, lane = tid & 63, w = tid >> 6;
  int l8 = lane >> 3;
  int sc = (lane & 7) ^ l8;
  int rbase = w * 8 + l8;
  // A: dense hb rows (rows >= Me hold finite poison, discarded by store guard)
  const unsigned short* pA00 = hb + ((size_t)e * CAP_ + m0 + rbase) * F_ + sc * 8;
  const unsigned short* pA01 = hb + ((size_t)e * CAP_ + m0 + 64 + rbase) * F_ + sc * 8;
  const unsigned short* pA10 = hb + ((size_t)e * CAP_ + m0 + 128 + rbase) * F_ + sc * 8;
  const unsigned short* pA11 = hb + ((size_t)e * CAP_ + m0 + 192 + rbase) * F_ + sc * 8;
  const unsigned short* pB00 = w2t + ((size_t)e * D_ + n0 + rbase) * F_ + sc * 8;
  const unsigned short* pB01 = w2t + ((size_t)e * D_ + n0 + 64 + rbase) * F_ + sc * 8;
  const unsigned short* pB10 = w2t + ((size_t)e * D_ + n0 + 128 + rbase) * F_ + sc * 8;
  const unsigned short* pB11 = w2t + ((size_t)e * D_ + n0 + 192 + rbase) * F_ + sc * 8;
  int fr = lane & 15, q = lane >> 4, fr7 = fr & 7;
  int wm = (w >> 2) * 128, wn = (w & 3) * 64;
  int wmo = wm * 64;
  int wno = (wn & 128) * 64;
  int wn64 = wn & 64;
  f32x4 acc[8][4] = {};
  bf16x8 alo[4][2], ahi[4][2], blo[2][2], bhi[2][2];

  STG_B(0, 0, 0); STG_B(0, 1, 0); STG_A(0, 0, 0); STG_A(0, 1, 0);
  STG_B(1, 0, 1); STG_B(1, 1, 1);
  WAITV4; BAR;

  const int NT = F_ / 64;   // 48
  for (int it = 0; it < NT / 2; ++it) {
    int t1 = 2 * it + 1, t2 = 2 * it + 2, t3 = 2 * it + 3;
    if (t2 > NT - 1) t2 = NT - 1;
    if (t3 > NT - 1) t3 = NT - 1;
    GROUP(0, t1, 1, t2, 0)
    GROUP(1, t2, 0, t3, 1)
  }

  int q4 = q * 4;
  #pragma unroll
  for (int i = 0; i < 8; ++i) {
    #pragma unroll
    for (int r = 0; r < 4; ++r) {
      int row = m0 + wm + i * 16 + q4 + r;
      if (row < Me) {
        int tok = tok_list[e * CAP_ + row];
        float pm = prob[tok];
        #pragma unroll
        for (int j = 0; j < 4; ++j) {
          int col = n0 + wn + j * 16 + fr;
          float v = (acc[i][j][r] + b2[e * D_ + col]) * pm;
          out[(size_t)tok * D_ + col] = v;
        }
      }
    }
  }
}

// ---------------- passthrough for dropped tokens ----------------
__global__ void passthrough_kernel(const float* __restrict__ x, const float* __restrict__ prob,
                                   const int* __restrict__ slot, float* __restrict__ out) {
  int t = blockIdx.x;
  if (slot[t] >= 0) return;
  float p = prob[t];
  for (int d = threadIdx.x; d < D_; d += 256)
    out[(size_t)t * D_ + d] = x[(size_t)t * D_ + d] * p;
}

extern "C" void kernel_launch(void* const* d_in, const int* in_sizes, int n_in,
                              void* d_out, int out_size, void* d_ws, size_t ws_size,
                              hipStream_t stream) {
  const float* x  = (const float*)d_in[0];
  const float* sw = (const float*)d_in[1];
  const float* sb = (const float*)d_in[2];
  const float* w1 = (const float*)d_in[3];
  const float* b1 = (const float*)d_in[4];
  const float* w2 = (const float*)d_in[5];
  const float* b2 = (const float*)d_in[6];
  float* out = (float*)d_out;
  (void)in_sizes; (void)n_in; (void)out_size; (void)ws_size;

  char* ws = (char*)d_ws;
  size_t off = 0;
  auto alloc = [&](size_t bytes) {
    char* p = ws + off;
    off = (off + bytes + 255) & ~(size_t)255;
    return p;
  };
  int* counts     = (int*)alloc(32 * sizeof(int));
  int* chunk_hist = (int*)alloc((size_t)NCHUNK_ * E_ * sizeof(int));
  int* chunk_off  = (int*)alloc((size_t)NCHUNK_ * E_ * sizeof(int));
  int* tok_list   = (int*)alloc((size_t)E_ * CAP_ * sizeof(int));
  int* route      = (int*)alloc((size_t)N_ * 4);
  float* prob     = (float*)alloc((size_t)N_ * 4);
  int* slot       = (int*)alloc((size_t)N_ * 4);
  unsigned short* xb  = (unsigned short*)alloc((size_t)N_ * D_ * 2);
  unsigned short* w1t = (unsigned short*)alloc((size_t)E_ * D_ * F_ * 2);
  unsigned short* w2t = (unsigned short*)alloc((size_t)E_ * D_ * F_ * 2);
  unsigned short* hb  = (unsigned short*)alloc((size_t)E_ * CAP_ * F_ * 2);

  dim3 tb(32, 8);
  tcast_kernel<<<dim3(F_ / 64, D_ / 64, E_), tb, 0, stream>>>(w1, w1t, D_, F_);
  tcast_kernel<<<dim3(D_ / 64, F_ / 64, E_), tb, 0, stream>>>(w2, w2t, F_, D_);
  router_kernel<<<N_ / 16, 256, 0, stream>>>(x, sw, sb, route, prob, xb);
  hist_kernel<<<NCHUNK_, 256, 0, stream>>>(route, chunk_hist);
  scan_kernel<<<1, NCHUNK_ * E_, 0, stream>>>(chunk_hist, chunk_off, counts);
  assign_kernel<<<NCHUNK_, 256, 0, stream>>>(route, prob, counts, chunk_off, tok_list, slot);
  gemm1_kernel<<<dim3(10, 12, 8), 512, 0, stream>>>(xb, w1t, b1, tok_list, counts, hb);
  gemm2_kernel<<<dim3(10, 3, 8), 512, 0, stream>>>(hb, w2t, b2, tok_list, counts, prob, out);
  passthrough_kernel<<<N_, 256, 0, stream>>>(x, prob, slot, out);
}

// Round 3
// 620.649 us; speedup vs baseline: 1.0068x; 1.0068x over previous
//
#include <hip/hip_runtime.h>
#include <cstdint>
#include <cstddef>

#define E_ 8
#define D_ 768
#define F_ 3072
#define N_ 16384
#define CAP_ 2560   // int(1.25 * 16384 / 8)
#define NCHUNK_ (N_ / 256)   // 64

typedef __attribute__((ext_vector_type(8))) short bf16x8;
typedef __attribute__((ext_vector_type(4))) float f32x4;

__device__ __forceinline__ unsigned short f2bf(float f) {
  unsigned u = __float_as_uint(f);
  u += 0x7fffu + ((u >> 16) & 1u);   // round-to-nearest-even
  return (unsigned short)(u >> 16);
}

__device__ __forceinline__ void gload16(const void* g, void* l) {
  __builtin_amdgcn_global_load_lds(
      (const __attribute__((address_space(1))) void*)g,
      (__attribute__((address_space(3))) void*)l, 16, 0, 0);
}

// inline-asm ds_read_b128: register-only operands -> opaque to SIInsertWaitcnts,
// so the compiler cannot inject s_waitcnt vmcnt(0) before it (the r2 killer).
// We manage lgkmcnt/vmcnt manually per the 8-phase plan.
template <int IMM>
__device__ __forceinline__ bf16x8 dsr(unsigned a) {
  bf16x8 r;
  asm volatile("ds_read_b128 %0, %1 offset:%2" : "=v"(r) : "v"(a), "n"(IMM));
  return r;
}

// ---------------- transpose + cast weights: src [E][R][C] fp32 -> dst [E][C][R] bf16 ----------------
__global__ void tcast_kernel(const float* __restrict__ src, unsigned short* __restrict__ dst,
                             int R, int C) {
  __shared__ float tile[64][65];
  int e = blockIdx.z;
  const float* s = src + (size_t)e * R * C;
  unsigned short* d = dst + (size_t)e * R * C;
  int c0 = blockIdx.x * 64, r0 = blockIdx.y * 64;
  int tx = threadIdx.x, ty = threadIdx.y;
  #pragma unroll
  for (int rr = ty; rr < 64; rr += 8) {
    tile[rr][tx]      = s[(size_t)(r0 + rr) * C + c0 + tx];
    tile[rr][tx + 32] = s[(size_t)(r0 + rr) * C + c0 + tx + 32];
  }
  __syncthreads();
  #pragma unroll
  for (int cc = ty; cc < 64; cc += 8) {
    ushort2 o;
    o.x = f2bf(tile[2 * tx][cc]);
    o.y = f2bf(tile[2 * tx + 1][cc]);
    *(ushort2*)&d[(size_t)(c0 + cc) * R + r0 + 2 * tx] = o;
  }
}

// ---------------- router (fused x->bf16 cast) ----------------
__global__ __launch_bounds__(256) void router_kernel(
    const float* __restrict__ x, const float* __restrict__ sw, const float* __restrict__ sb,
    int* __restrict__ route, float* __restrict__ prob,
    unsigned short* __restrict__ xb) {
  __shared__ float wl[E_ * D_];
  int tid = threadIdx.x;
  #pragma unroll
  for (int ee = 0; ee < E_; ++ee)
    for (int dd = tid; dd < D_; dd += 256)
      wl[ee * D_ + dd] = sw[dd * E_ + ee];
  __syncthreads();
  int wave = tid >> 6, lane = tid & 63;
  int tbase = blockIdx.x * 16 + wave * 4;
  #pragma unroll
  for (int tt = 0; tt < 4; ++tt) {
    int t = tbase + tt;
    const float* xp = x + (size_t)t * D_;
    unsigned short* xbp = xb + (size_t)t * D_;
    float acc[E_];
    #pragma unroll
    for (int e = 0; e < E_; ++e) acc[e] = 0.f;
    #pragma unroll
    for (int r = 0; r < D_ / 64; ++r) {
      int dd = r * 64 + lane;
      float xv = xp[dd];
      xbp[dd] = f2bf(xv);
      #pragma unroll
      for (int e = 0; e < E_; ++e) acc[e] += xv * wl[e * D_ + dd];
    }
    #pragma unroll
    for (int e = 0; e < E_; ++e) {
      #pragma unroll
      for (int o = 32; o > 0; o >>= 1) acc[e] += __shfl_xor(acc[e], o);
    }
    if (lane == 0) {
      float mx = -1e30f; int arg = 0;
      #pragma unroll
      for (int e = 0; e < E_; ++e) {
        float l = acc[e] + sb[e];
        acc[e] = l;
        if (l > mx) { mx = l; arg = e; }
      }
      float s = 0.f;
      #pragma unroll
      for (int e = 0; e < E_; ++e) s += expf(acc[e] - mx);
      route[t] = arg;
      prob[t] = 1.f / s;
    }
  }
}

// ---------------- per-chunk histogram ----------------
__global__ void hist_kernel(const int* __restrict__ route, int* __restrict__ chunk_hist) {
  __shared__ int h[E_];
  int tid = threadIdx.x;
  if (tid < E_) h[tid] = 0;
  __syncthreads();
  atomicAdd(&h[route[blockIdx.x * 256 + tid]], 1);
  __syncthreads();
  if (tid < E_) chunk_hist[blockIdx.x * E_ + tid] = h[tid];
}

// ---------------- exclusive scan over chunks per expert ----------------
__global__ void scan_kernel(const int* __restrict__ chunk_hist, int* __restrict__ chunk_off,
                            int* __restrict__ counts) {
  __shared__ int h[NCHUNK_ * E_];
  int tid = threadIdx.x;
  h[tid] = chunk_hist[tid];
  __syncthreads();
  if (tid < E_) {
    int run = 0;
    for (int c = 0; c < NCHUNK_; ++c) {
      chunk_off[c * E_ + tid] = run;
      run += h[c * E_ + tid];
    }
    counts[tid] = run;
  }
}

// ---------------- slot assignment ----------------
__global__ void assign_kernel(const int* __restrict__ route, const float* __restrict__ prob,
                              const int* __restrict__ counts, const int* __restrict__ chunk_off,
                              int* __restrict__ tok_list, int* __restrict__ slot) {
  __shared__ int rt[256];
  int tid = threadIdx.x;
  int i = blockIdx.x * 256 + tid;
  int e = route[i];
  rt[tid] = e;
  __syncthreads();
  int r = 0;
  for (int j = 0; j < tid; ++j) r += (rt[j] == e) ? 1 : 0;
  int c = counts[e];
  int s; bool keep;
  if (c <= CAP_) {
    s = chunk_off[blockIdx.x * E_ + e] + r;
    keep = true;
  } else {
    float p = prob[i];
    int rr = 0;
    for (int j = 0; j < N_; ++j) {
      if (route[j] == e) {
        float pj = prob[j];
        rr += (pj > p || (pj == p && j < i)) ? 1 : 0;
      }
    }
    s = rr; keep = (rr < CAP_);
  }
  if (keep) tok_list[e * CAP_ + s] = i;
  slot[i] = keep ? s : -1;
}

// =====================================================================================
// 256x256 / BK=64 grouped GEMMs, 8 waves (2Mx4N), 128 KiB dbuf LDS, 8-phase
// counted-vmcnt schedule with INLINE-ASM ds_read_b128 (no compiler vmcnt drains).
// Per-thread 32-bit LDS read bases (kh selected via XOR 64 on the chunk-swizzle bits);
// compile-time offset: immediates for the row walk.
// Wait plan (proof in r2 notes, unchanged): vmcnt(4) at group phases 4 and 8 only;
// per-phase s_waitcnt lgkmcnt(0)+sched_barrier(0) after the barrier, before MFMA.
// =====================================================================================

#define RD_A(dst, c, i0)                                    \
  dst[0][0] = dsr<((i0)+0)*2048>(aB##c##k0);                \
  dst[0][1] = dsr<((i0)+0)*2048>(aB##c##k1);                \
  dst[1][0] = dsr<((i0)+1)*2048>(aB##c##k0);                \
  dst[1][1] = dsr<((i0)+1)*2048>(aB##c##k1);                \
  dst[2][0] = dsr<((i0)+2)*2048>(aB##c##k0);                \
  dst[2][1] = dsr<((i0)+2)*2048>(aB##c##k1);                \
  dst[3][0] = dsr<((i0)+3)*2048>(aB##c##k0);                \
  dst[3][1] = dsr<((i0)+3)*2048>(aB##c##k1);

#define RD_B(dst, c, j0)                                    \
  dst[0][0] = dsr<((j0)+0)*2048>(bB##c##k0);                \
  dst[0][1] = dsr<((j0)+0)*2048>(bB##c##k1);                \
  dst[1][0] = dsr<((j0)+1)*2048>(bB##c##k0);                \
  dst[1][1] = dsr<((j0)+1)*2048>(bB##c##k1);

#define MM(i0, j0, A_, B_)                                                        \
  _Pragma("unroll") for (int ii = 0; ii < 4; ++ii)                                \
  _Pragma("unroll") for (int jj = 0; jj < 2; ++jj)                                \
  _Pragma("unroll") for (int kh = 0; kh < 2; ++kh)                                \
    acc[i0 + ii][j0 + jj] = __builtin_amdgcn_mfma_f32_16x16x32_bf16(              \
        A_[ii][kh], B_[jj][kh], acc[i0 + ii][j0 + jj], 0, 0, 0);

#define STG_A(tb, h, t) {                                                         \
  gload16(pA##h##0 + (size_t)(t) * 64, smb + (tb) * 65536 + (h) * 16384 + w * 1024);            \
  gload16(pA##h##1 + (size_t)(t) * 64, smb + (tb) * 65536 + (h) * 16384 + 8192 + w * 1024); }

#define STG_B(tb, h, t) {                                                         \
  gload16(pB##h##0 + (size_t)(t) * 64, smb + (tb) * 65536 + 32768 + (h) * 16384 + w * 1024);    \
  gload16(pB##h##1 + (size_t)(t) * 64, smb + (tb) * 65536 + 32768 + (h) * 16384 + 8192 + w * 1024); }

#define BAR __builtin_amdgcn_s_barrier()
#define PRIO1 __builtin_amdgcn_s_setprio(1)
#define PRIO0 __builtin_amdgcn_s_setprio(0)
#define WAITV4 asm volatile("s_waitcnt vmcnt(4)" ::: "memory")
#define WAITL0 { asm volatile("s_waitcnt lgkmcnt(0)"); __builtin_amdgcn_sched_barrier(0); }

#define GROUP(cb, ta, tgtA, tb_, tgtB)                                            \
  RD_A(alo, cb, 0); RD_B(blo, cb, 0); STG_A(tgtA, 0, ta);                         \
  BAR; WAITL0; PRIO1; MM(0, 0, alo, blo); PRIO0; BAR;                             \
  RD_B(bhi, cb, 2); STG_A(tgtA, 1, ta);                                           \
  BAR; WAITL0; PRIO1; MM(0, 2, alo, bhi); PRIO0; BAR;                             \
  RD_A(ahi, cb, 4); STG_B(tgtB, 0, tb_);                                          \
  BAR; WAITL0; PRIO1; MM(4, 0, ahi, blo); PRIO0; BAR;                             \
  STG_B(tgtB, 1, tb_);                                                            \
  BAR; PRIO1; MM(4, 2, ahi, bhi); PRIO0; WAITV4; BAR;

// ---------------- GEMM1: h[e][m][f] = gelu( x[tok] @ w1[e] + b1[e] ) ----------------
__global__ __launch_bounds__(512, 2) void gemm1_kernel(
    const unsigned short* __restrict__ xb, const unsigned short* __restrict__ w1t,
    const float* __restrict__ b1, const int* __restrict__ tok_list,
    const int* __restrict__ counts, unsigned short* __restrict__ hb) {
  // T1: XCD-chunked swizzle (960 blocks % 8 == 0)
  int flat = blockIdx.x + 10 * (blockIdx.y + 12 * blockIdx.z);
  int work = (flat & 7) * 120 + (flat >> 3);
  int xm = work % 10;
  int rest = work / 10;
  int yn = rest % 12;
  int e = rest / 12;
  int Me = counts[e] < CAP_ ? counts[e] : CAP_;
  int m0 = xm * 256;
  if (m0 >= Me) return;
  int n0 = yn * 256;
  __shared__ unsigned short sm[65536];   // 128 KiB
  char* smb = (char*)sm;
  int tid = threadIdx.x, lane = tid & 63, w = tid >> 6;
  // staging geometry
  int l8 = lane >> 3;
  int sc = (lane & 7) ^ l8;              // pre-swizzled source chunk
  int rbase = w * 8 + l8;                // 0..63
  int ra00 = m0 + rbase;       if (ra00 > Me - 1) ra00 = Me - 1;
  int ra01 = m0 + 64 + rbase;  if (ra01 > Me - 1) ra01 = Me - 1;
  int ra10 = m0 + 128 + rbase; if (ra10 > Me - 1) ra10 = Me - 1;
  int ra11 = m0 + 192 + rbase; if (ra11 > Me - 1) ra11 = Me - 1;
  const unsigned short* pA00 = xb + (size_t)tok_list[e * CAP_ + ra00] * D_ + sc * 8;
  const unsigned short* pA01 = xb + (size_t)tok_list[e * CAP_ + ra01] * D_ + sc * 8;
  const unsigned short* pA10 = xb + (size_t)tok_list[e * CAP_ + ra10] * D_ + sc * 8;
  const unsigned short* pA11 = xb + (size_t)tok_list[e * CAP_ + ra11] * D_ + sc * 8;
  const unsigned short* pB00 = w1t + ((size_t)e * F_ + n0 + rbase) * D_ + sc * 8;
  const unsigned short* pB01 = w1t + ((size_t)e * F_ + n0 + 64 + rbase) * D_ + sc * 8;
  const unsigned short* pB10 = w1t + ((size_t)e * F_ + n0 + 128 + rbase) * D_ + sc * 8;
  const unsigned short* pB11 = w1t + ((size_t)e * F_ + n0 + 192 + rbase) * D_ + sc * 8;
  // fragment geometry
  int fr = lane & 15, q = lane >> 4, fr7 = fr & 7;
  int wm = (w >> 2) * 128, wn = (w & 3) * 64;
  // 32-bit LDS read bases (bytes)
  unsigned smoff = (unsigned)(uintptr_t)(__attribute__((address_space(3))) unsigned short*)sm;
  unsigned c0a = (unsigned)((q ^ fr7) * 16);
  unsigned aB0k0 = smoff + (unsigned)((w >> 2) * 16384 + fr * 128) + c0a;
  unsigned aB0k1 = aB0k0 ^ 64u;
  unsigned aB1k0 = aB0k0 + 65536u;
  unsigned aB1k1 = aB1k0 ^ 64u;
  unsigned bB0k0 = smoff + 32768u + (unsigned)((wn & 128) * 128 + (wn & 64) * 128 + fr * 128) + c0a;
  unsigned bB0k1 = bB0k0 ^ 64u;
  unsigned bB1k0 = bB0k0 + 65536u;
  unsigned bB1k1 = bB1k0 ^ 64u;
  f32x4 acc[8][4] = {};
  bf16x8 alo[4][2], ahi[4][2], blo[2][2], bhi[2][2];

  // prologue: buf0 <- tile0 (all 4 halves), buf1 <- tile1 B-halves
  STG_B(0, 0, 0); STG_B(0, 1, 0); STG_A(0, 0, 0); STG_A(0, 1, 0);
  STG_B(1, 0, 1); STG_B(1, 1, 1);
  WAITV4; BAR;

  const int NT = D_ / 64;   // 12
  for (int it = 0; it < NT / 2; ++it) {
    int t1 = 2 * it + 1, t2 = 2 * it + 2, t3 = 2 * it + 3;
    if (t2 > NT - 1) t2 = NT - 1;    // tail: redundant re-stage into dead slots
    if (t3 > NT - 1) t3 = NT - 1;
    GROUP(0, t1, 1, t2, 0)
    GROUP(1, t2, 0, t3, 1)
  }

  int q4 = q * 4;
  #pragma unroll
  for (int i = 0; i < 8; ++i) {
    #pragma unroll
    for (int j = 0; j < 4; ++j) {
      int col = n0 + wn + j * 16 + fr;
      float bias = b1[e * F_ + col];
      #pragma unroll
      for (int r = 0; r < 4; ++r) {
        int row = m0 + wm + i * 16 + q4 + r;
        if (row < Me) {
          float v = acc[i][j][r] + bias;
          v = 0.5f * v * (1.f + erff(v * 0.70710678118654752f));   // exact GELU
          hb[((size_t)e * CAP_ + row) * F_ + col] = f2bf(v);
        }
      }
    }
  }
}

// ---------------- GEMM2: out[tok] = (h[e] @ w2[e] + b2[e]) * prob[tok] ----------------
__global__ __launch_bounds__(512, 2) void gemm2_kernel(
    const unsigned short* __restrict__ hb, const unsigned short* __restrict__ w2t,
    const float* __restrict__ b2, const int* __restrict__ tok_list,
    const int* __restrict__ counts, const float* __restrict__ prob,
    float* __restrict__ out) {
  // T1 swizzle (240 blocks % 8 == 0)
  int flat = blockIdx.x + 10 * (blockIdx.y + 3 * blockIdx.z);
  int work = (flat & 7) * 30 + (flat >> 3);
  int xm = work % 10;
  int rest = work / 10;
  int yn = rest % 3;
  int e = rest / 3;
  int Me = counts[e] < CAP_ ? counts[e] : CAP_;
  int m0 = xm * 256;
  if (m0 >= Me) return;
  int n0 = yn * 256;
  __shared__ unsigned short sm[65536];
  char* smb = (char*)sm;
  int tid = threadIdx.x, lane = tid & 63, w = tid >> 6;
  int l8 = lane >> 3;
  int sc = (lane & 7) ^ l8;
  int rbase = w * 8 + l8;
  // A: dense hb rows (rows >= Me hold finite poison, discarded by store guard)
  const unsigned short* pA00 = hb + ((size_t)e * CAP_ + m0 + rbase) * F_ + sc * 8;
  const unsigned short* pA01 = hb + ((size_t)e * CAP_ + m0 + 64 + rbase) * F_ + sc * 8;
  const unsigned short* pA10 = hb + ((size_t)e * CAP_ + m0 + 128 + rbase) * F_ + sc * 8;
  const unsigned short* pA11 = hb + ((size_t)e * CAP_ + m0 + 192 + rbase) * F_ + sc * 8;
  const unsigned short* pB00 = w2t + ((size_t)e * D_ + n0 + rbase) * F_ + sc * 8;
  const unsigned short* pB01 = w2t + ((size_t)e * D_ + n0 + 64 + rbase) * F_ + sc * 8;
  const unsigned short* pB10 = w2t + ((size_t)e * D_ + n0 + 128 + rbase) * F_ + sc * 8;
  const unsigned short* pB11 = w2t + ((size_t)e * D_ + n0 + 192 + rbase) * F_ + sc * 8;
  int fr = lane & 15, q = lane >> 4, fr7 = fr & 7;
  int wm = (w >> 2) * 128, wn = (w & 3) * 64;
  unsigned smoff = (unsigned)(uintptr_t)(__attribute__((address_space(3))) unsigned short*)sm;
  unsigned c0a = (unsigned)((q ^ fr7) * 16);
  unsigned aB0k0 = smoff + (unsigned)((w >> 2) * 16384 + fr * 128) + c0a;
  unsigned aB0k1 = aB0k0 ^ 64u;
  unsigned aB1k0 = aB0k0 + 65536u;
  unsigned aB1k1 = aB1k0 ^ 64u;
  unsigned bB0k0 = smoff + 32768u + (unsigned)((wn & 128) * 128 + (wn & 64) * 128 + fr * 128) + c0a;
  unsigned bB0k1 = bB0k0 ^ 64u;
  unsigned bB1k0 = bB0k0 + 65536u;
  unsigned bB1k1 = bB1k0 ^ 64u;
  f32x4 acc[8][4] = {};
  bf16x8 alo[4][2], ahi[4][2], blo[2][2], bhi[2][2];

  STG_B(0, 0, 0); STG_B(0, 1, 0); STG_A(0, 0, 0); STG_A(0, 1, 0);
  STG_B(1, 0, 1); STG_B(1, 1, 1);
  WAITV4; BAR;

  const int NT = F_ / 64;   // 48
  for (int it = 0; it < NT / 2; ++it) {
    int t1 = 2 * it + 1, t2 = 2 * it + 2, t3 = 2 * it + 3;
    if (t2 > NT - 1) t2 = NT - 1;
    if (t3 > NT - 1) t3 = NT - 1;
    GROUP(0, t1, 1, t2, 0)
    GROUP(1, t2, 0, t3, 1)
  }

  int q4 = q * 4;
  #pragma unroll
  for (int i = 0; i < 8; ++i) {
    #pragma unroll
    for (int r = 0; r < 4; ++r) {
      int row = m0 + wm + i * 16 + q4 + r;
      if (row < Me) {
        int tok = tok_list[e * CAP_ + row];
        float pm = prob[tok];
        #pragma unroll
        for (int j = 0; j < 4; ++j) {
          int col = n0 + wn + j * 16 + fr;
          float v = (acc[i][j][r] + b2[e * D_ + col]) * pm;
          out[(size_t)tok * D_ + col] = v;
        }
      }
    }
  }
}

// ---------------- passthrough for dropped tokens ----------------
__global__ void passthrough_kernel(const float* __restrict__ x, const float* __restrict__ prob,
                                   const int* __restrict__ slot, float* __restrict__ out) {
  int t = blockIdx.x;
  if (slot[t] >= 0) return;
  float p = prob[t];
  for (int d = threadIdx.x; d < D_; d += 256)
    out[(size_t)t * D_ + d] = x[(size_t)t * D_ + d] * p;
}

extern "C" void kernel_launch(void* const* d_in, const int* in_sizes, int n_in,
                              void* d_out, int out_size, void* d_ws, size_t ws_size,
                              hipStream_t stream) {
  const float* x  = (const float*)d_in[0];
  const float* sw = (const float*)d_in[1];
  const float* sb = (const float*)d_in[2];
  const float* w1 = (const float*)d_in[3];
  const float* b1 = (const float*)d_in[4];
  const float* w2 = (const float*)d_in[5];
  const float* b2 = (const float*)d_in[6];
  float* out = (float*)d_out;
  (void)in_sizes; (void)n_in; (void)out_size; (void)ws_size;

  char* ws = (char*)d_ws;
  size_t off = 0;
  auto alloc = [&](size_t bytes) {
    char* p = ws + off;
    off = (off + bytes + 255) & ~(size_t)255;
    return p;
  };
  int* counts     = (int*)alloc(32 * sizeof(int));
  int* chunk_hist = (int*)alloc((size_t)NCHUNK_ * E_ * sizeof(int));
  int* chunk_off  = (int*)alloc((size_t)NCHUNK_ * E_ * sizeof(int));
  int* tok_list   = (int*)alloc((size_t)E_ * CAP_ * sizeof(int));
  int* route      = (int*)alloc((size_t)N_ * 4);
  float* prob     = (float*)alloc((size_t)N_ * 4);
  int* slot       = (int*)alloc((size_t)N_ * 4);
  unsigned short* xb  = (unsigned short*)alloc((size_t)N_ * D_ * 2);
  unsigned short* w1t = (unsigned short*)alloc((size_t)E_ * D_ * F_ * 2);
  unsigned short* w2t = (unsigned short*)alloc((size_t)E_ * D_ * F_ * 2);
  unsigned short* hb  = (unsigned short*)alloc((size_t)E_ * CAP_ * F_ * 2);

  dim3 tb(32, 8);
  tcast_kernel<<<dim3(F_ / 64, D_ / 64, E_), tb, 0, stream>>>(w1, w1t, D_, F_);
  tcast_kernel<<<dim3(D_ / 64, F_ / 64, E_), tb, 0, stream>>>(w2, w2t, F_, D_);
  router_kernel<<<N_ / 16, 256, 0, stream>>>(x, sw, sb, route, prob, xb);
  hist_kernel<<<NCHUNK_, 256, 0, stream>>>(route, chunk_hist);
  scan_kernel<<<1, NCHUNK_ * E_, 0, stream>>>(chunk_hist, chunk_off, counts);
  assign_kernel<<<NCHUNK_, 256, 0, stream>>>(route, prob, counts, chunk_off, tok_list, slot);
  gemm1_kernel<<<dim3(10, 12, 8), 512, 0, stream>>>(xb, w1t, b1, tok_list, counts, hb);
  gemm2_kernel<<<dim3(10, 3, 8), 512, 0, stream>>>(hb, w2t, b2, tok_list, counts, prob, out);
  passthrough_kernel<<<N_, 256, 0, stream>>>(x, prob, slot, out);
}